// Round 6
// baseline (176.128 us; speedup 1.0000x reference)
//
#include <hip/hip_runtime.h>
#include <hip/hip_bf16.h>

typedef unsigned short ushort_t;
typedef __attribute__((ext_vector_type(8))) short short8;   // 8 bf16 (4 VGPRs)
typedef __attribute__((ext_vector_type(4))) short short4v;  // 4 bf16
typedef __attribute__((ext_vector_type(4))) float f32x4;    // 4 fp32 acc

__device__ __forceinline__ float bf2f(ushort_t u) {
    unsigned int x = ((unsigned int)u) << 16;
    float f; __builtin_memcpy(&f, &x, 4); return f;
}
__device__ __forceinline__ ushort_t f2bf(float f) {
    unsigned int x; __builtin_memcpy(&x, &f, 4);
    x += 0x7fff + ((x >> 16) & 1);
    return (ushort_t)(x >> 16);
}

// async global->LDS, 16B per lane; LDS dest = wave-uniform base + lane*16
__device__ __forceinline__ void gl_lds16(const void* g, void* l) {
    __builtin_amdgcn_global_load_lds(
        (const __attribute__((address_space(1))) void*)g,
        (__attribute__((address_space(3))) void*)l, 16, 0, 0);
}

constexpr int E  = 1024;
constexpr int Hd = 64;
constexpr int S  = 2048;
constexpr int ROWS = 8 * 2048;   // 16384
constexpr int NTOT = 192;        // Q|K|V output columns
constexpr int SPB  = 288;        // partial slots per batch (sum of chunks/qtile)

// ---------------------------------------------------------------------------
// prep: WT[192][1024] bf16, rows 0-63 = Wq^T, 64-127 = Wk^T, 128-191 = Wv^T
__global__ __launch_bounds__(256)
void prep_wt(const float* __restrict__ Wk, const float* __restrict__ Wq,
             const float* __restrict__ Wv, ushort_t* __restrict__ WT)
{
    int idx = blockIdx.x * 256 + threadIdx.x;
    int n = idx >> 10;
    int kk = idx & 1023;
    const float* W = (n < 64) ? Wq : ((n < 128) ? Wk : Wv);
    int h = n & 63;
    WT[idx] = f2bf(W[kk * Hd + h]);
}

// ---------------------------------------------------------------------------
// Projection GEMM v4: block = 16 M-rows x 192 N-cols, K-chunk 64, grid 1024.
// WT chunk staged async with a granule-rotate swizzle: LDS slot (n, js) holds
// WT granule (n, (js+n)&7); reads use js=(jreq-n)&7 -> banks 4*((g-m+c)&7),
// 2-way only (free). x chunk fp32->bf16 via VGPRs. Wave w owns N-tiles
// {w, 4+w, 8+w} (one each of q/k/v). q written pre-scaled by 1/8.
__global__ __launch_bounds__(256)
void proj_mfma(const float* __restrict__ x, const ushort_t* __restrict__ WT,
               ushort_t* __restrict__ qo, ushort_t* __restrict__ ko,
               ushort_t* __restrict__ vo)
{
    __shared__ alignas(16) ushort_t WTS[NTOT * 64];   // swizzled granules
    __shared__ alignas(16) ushort_t XS[16][72];       // [m][k], stride 144 B

    const int t    = threadIdx.x;
    const int w    = t >> 6;
    const int lane = t & 63;
    const int m    = lane & 15;
    const int g    = lane >> 4;
    const int rb   = blockIdx.x * 16;

    f32x4 acc[3];
    #pragma unroll
    for (int j = 0; j < 3; ++j) acc[j] = (f32x4){0.f, 0.f, 0.f, 0.f};

    const int xrow = t >> 4;            // 0..15
    const int xc4  = (t & 15) * 4;      // 0..60
    const float* xp0 = x + (size_t)(rb + xrow) * E + xc4;

    for (int c = 0; c < E / 64; ++c) {
        const int k0 = c * 64;

        // ---- async-stage WT slice [192][64], granule-rotated
        #pragma unroll
        for (int it = 0; it < 6; ++it) {
            const int f  = it * 256 + t;               // dest granule id
            const int n  = f >> 3;
            const int js = f & 7;
            const ushort_t* gp = WT + (size_t)n * E + k0 + ((js + n) & 7) * 8;
            gl_lds16(gp, &WTS[(it * 256 + w * 64) * 8]);
        }

        // ---- stage x slice [16][64] fp32 -> bf16
        {
            float4 xa = *(const float4*)(xp0 + k0);
            short4v a4;
            a4[0] = (short)f2bf(xa.x); a4[1] = (short)f2bf(xa.y);
            a4[2] = (short)f2bf(xa.z); a4[3] = (short)f2bf(xa.w);
            *(short4v*)&XS[xrow][xc4] = a4;
        }
        __syncthreads();   // drains vmcnt (async WT) + lgkm (x writes)

        #pragma unroll
        for (int kt = 0; kt < 2; ++kt) {
            short8 a = *(const short8*)&XS[m][kt * 32 + g * 8];
            #pragma unroll
            for (int j = 0; j < 3; ++j) {
                const int nt   = j * 4 + w;
                const int n    = nt * 16 + m;
                const int jreq = kt * 4 + g;
                short8 b = *(const short8*)&WTS[n * 64 + ((jreq - n) & 7) * 8];
                acc[j] = __builtin_amdgcn_mfma_f32_16x16x32_bf16(a, b, acc[j], 0, 0, 0);
            }
        }
        __syncthreads();
    }

    // ---- epilogue: C/D row = g*4+r, col = w*16+m; tiles 0-3=q, 4-7=k, 8-11=v
    const int orow = rb + g * 4;
    const int col  = w * 16 + m;
    #pragma unroll
    for (int r = 0; r < 4; ++r)
        qo[(size_t)(orow + r) * Hd + col] = f2bf(acc[0][r] * 0.125f);
    #pragma unroll
    for (int r = 0; r < 4; ++r)
        ko[(size_t)(orow + r) * Hd + col] = f2bf(acc[1][r]);
    #pragma unroll
    for (int r = 0; r < 4; ++r)
        vo[(size_t)(orow + r) * Hd + col] = f2bf(acc[2][r]);
}

// ---------------------------------------------------------------------------
// Attention phase 1 (split-K): block = (batch, q-tile of 32 rows, 256-key
// chunk). 4 waves = 2 q-subtiles x 2 key parities; <=2 super-iters of 128
// keys. Writes partial (m, l, unnormalized O bf16) per slot.
// slot = batch*288 + (g8+1)*(qt-4*g8) + chunk, g8 = qt>>3.
__global__ __launch_bounds__(256)
void attn_part(const ushort_t* __restrict__ q, const ushort_t* __restrict__ k,
               const ushort_t* __restrict__ v, float* __restrict__ mp,
               float* __restrict__ lp, ushort_t* __restrict__ op)
{
    const int id    = blockIdx.x;
    const int chunk = id >> 9;           // 0..7
    const int bq    = id & 511;
    const int batch = bq >> 6;
    const int qt    = bq & 63;
    const int g8    = qt >> 3;
    if (chunk > g8) return;              // block-uniform exit

    const int qs0      = qt * 32;
    const int key0base = chunk * 256;
    const int nkeys    = min(256, qs0 + 32 - key0base);
    const int nsup     = (nkeys + 127) >> 7;   // 1 or 2
    const int slot     = batch * SPB + (g8 + 1) * (qt - 4 * g8) + chunk;

    const ushort_t* kb = k + (size_t)batch * S * Hd;
    const ushort_t* vb = v + (size_t)batch * S * Hd;

    const int t    = threadIdx.x;
    const int w    = t >> 6;
    const int lane = t & 63;
    const int m    = lane & 15;
    const int g    = lane >> 4;
    const int i    = w & 1;              // q-subtile (16 rows)
    const int p    = w >> 1;             // key parity half
    const int rowmax = qs0 + i * 16 + 15;

    __shared__ alignas(16) ushort_t VT[Hd][136];    // [h][key 0..127]
    __shared__ alignas(16) ushort_t PL[4][16][72];  // per-wave P roundtrip
    __shared__ float OB[2][2][16][64];              // [i][p][row][col]
    __shared__ float ML[2][2][16], LL[2][2][16];

    const ushort_t* qrow = q + (size_t)(batch * S + qs0 + i * 16 + m) * Hd;
    short8 qf0 = *(const short8*)(qrow + g * 8);
    short8 qf1 = *(const short8*)(qrow + 32 + g * 8);

    f32x4 o[4];
    #pragma unroll
    for (int j = 0; j < 4; ++j) o[j] = (f32x4){0.f, 0.f, 0.f, 0.f};
    float mrun[4] = {-INFINITY, -INFINITY, -INFINITY, -INFINITY};
    float lrun[4] = {0.f, 0.f, 0.f, 0.f};

    const int skl = (w & 1) * 64 + lane;     // V-stage key 0..127
    const int sh0 = (w >> 1) * 32;           // V-stage h base

    for (int s = 0; s < nsup; ++s) {
        const int key0s = key0base + s * 128;

        // ---- stage V^T (clamp OOB keys; they're masked to p=0 anyway)
        {
            const int gk = min(key0s + skl, S - 1);
            const ushort_t* vr = vb + (size_t)gk * Hd + sh0;
            #pragma unroll
            for (int c = 0; c < 4; ++c) {
                uint4 u = *(const uint4*)(vr + c * 8);
                VT[sh0 + c*8 + 0][skl] = (ushort_t)(u.x & 0xffff);
                VT[sh0 + c*8 + 1][skl] = (ushort_t)(u.x >> 16);
                VT[sh0 + c*8 + 2][skl] = (ushort_t)(u.y & 0xffff);
                VT[sh0 + c*8 + 3][skl] = (ushort_t)(u.y >> 16);
                VT[sh0 + c*8 + 4][skl] = (ushort_t)(u.z & 0xffff);
                VT[sh0 + c*8 + 5][skl] = (ushort_t)(u.z >> 16);
                VT[sh0 + c*8 + 6][skl] = (ushort_t)(u.w & 0xffff);
                VT[sh0 + c*8 + 7][skl] = (ushort_t)(u.w >> 16);
            }
        }
        __syncthreads();

        const int key0p = key0s + p * 64;
        if (key0p <= rowmax) {
            // ---- S = Q K^T
            f32x4 sacc[4];
            #pragma unroll
            for (int j = 0; j < 4; ++j) sacc[j] = (f32x4){0.f, 0.f, 0.f, 0.f};
            #pragma unroll
            for (int nt = 0; nt < 4; ++nt) {
                const int keyg = min(key0p + nt * 16 + m, S - 1);
                const ushort_t* krow = kb + (size_t)keyg * Hd;
                short8 b0 = *(const short8*)(krow + g * 8);
                short8 b1 = *(const short8*)(krow + 32 + g * 8);
                sacc[nt] = __builtin_amdgcn_mfma_f32_16x16x32_bf16(qf0, b0, sacc[nt], 0, 0, 0);
                sacc[nt] = __builtin_amdgcn_mfma_f32_16x16x32_bf16(qf1, b1, sacc[nt], 0, 0, 0);
            }

            // ---- causal mask (diagonal proximity only)
            if (key0p + 63 > qs0 + i * 16) {
                const int rowg = qs0 + i * 16 + g * 4;
                #pragma unroll
                for (int nt = 0; nt < 4; ++nt) {
                    const int keyg = key0p + nt * 16 + m;
                    #pragma unroll
                    for (int r = 0; r < 4; ++r)
                        if (keyg > rowg + r) sacc[nt][r] = -INFINITY;
                }
            }

            // ---- online softmax (rows across 16-lane groups)
            float msafe[4], alpha[4];
            #pragma unroll
            for (int r = 0; r < 4; ++r) {
                float tm = fmaxf(fmaxf(sacc[0][r], sacc[1][r]),
                                 fmaxf(sacc[2][r], sacc[3][r]));
                #pragma unroll
                for (int d = 1; d < 16; d <<= 1) tm = fmaxf(tm, __shfl_xor(tm, d, 64));
                float mn = fmaxf(mrun[r], tm);
                msafe[r] = (mn == -INFINITY) ? 0.f : mn;
                alpha[r] = __expf(mrun[r] - msafe[r]);
                mrun[r]  = mn;
            }
            #pragma unroll
            for (int nt = 0; nt < 4; ++nt)
                #pragma unroll
                for (int r = 0; r < 4; ++r)
                    sacc[nt][r] = __expf(sacc[nt][r] - msafe[r]);
            #pragma unroll
            for (int r = 0; r < 4; ++r) {
                float ts = sacc[0][r] + sacc[1][r] + sacc[2][r] + sacc[3][r];
                #pragma unroll
                for (int d = 1; d < 16; d <<= 1) ts += __shfl_xor(ts, d, 64);
                lrun[r] = lrun[r] * alpha[r] + ts;
            }
            #pragma unroll
            for (int nt = 0; nt < 4; ++nt)
                #pragma unroll
                for (int r = 0; r < 4; ++r)
                    o[nt][r] *= alpha[r];

            // ---- P: C-layout -> per-wave LDS -> A-layout
            #pragma unroll
            for (int nt = 0; nt < 4; ++nt)
                #pragma unroll
                for (int r = 0; r < 4; ++r)
                    PL[w][g * 4 + r][nt * 16 + m] = f2bf(sacc[nt][r]);

            short8 pa0 = *(const short8*)&PL[w][m][g * 8];
            short8 pa1 = *(const short8*)&PL[w][m][32 + g * 8];

            // ---- O += P V
            const int vo0 = p * 64;
            #pragma unroll
            for (int nt = 0; nt < 4; ++nt) {
                short8 vb0 = *(const short8*)&VT[nt * 16 + m][vo0 + g * 8];
                short8 vb1 = *(const short8*)&VT[nt * 16 + m][vo0 + 32 + g * 8];
                o[nt] = __builtin_amdgcn_mfma_f32_16x16x32_bf16(pa0, vb0, o[nt], 0, 0, 0);
                o[nt] = __builtin_amdgcn_mfma_f32_16x16x32_bf16(pa1, vb1, o[nt], 0, 0, 0);
            }
        }
        __syncthreads();
    }

    // ---- cross-parity merge, then write partial (m, l, O)
    if (m == 0) {
        #pragma unroll
        for (int r = 0; r < 4; ++r) {
            ML[i][p][g * 4 + r] = mrun[r];
            LL[i][p][g * 4 + r] = lrun[r];
        }
    }
    #pragma unroll
    for (int nt = 0; nt < 4; ++nt)
        #pragma unroll
        for (int r = 0; r < 4; ++r)
            OB[i][p][g * 4 + r][nt * 16 + m] = o[nt][r];
    __syncthreads();

    if (p == 0) {
        float a[4], bsc[4];
        #pragma unroll
        for (int r = 0; r < 4; ++r) {
            const int rl = g * 4 + r;
            float mA = ML[i][0][rl], mB = ML[i][1][rl];
            float mm = fmaxf(mA, mB);
            float ms = (mm == -INFINITY) ? 0.f : mm;
            a[r]   = __expf(mA - ms);
            bsc[r] = __expf(mB - ms);
            if (m == 0) {
                mp[slot * 32 + i * 16 + rl] = ms;
                lp[slot * 32 + i * 16 + rl] =
                    LL[i][0][rl] * a[r] + LL[i][1][rl] * bsc[r];
            }
        }
        #pragma unroll
        for (int nt = 0; nt < 4; ++nt)
            #pragma unroll
            for (int r = 0; r < 4; ++r) {
                const int rl = g * 4 + r, col = nt * 16 + m;
                float oo = OB[i][0][rl][col] * a[r] + OB[i][1][rl][col] * bsc[r];
                op[(size_t)slot * 2048 + (i * 16 + rl) * 64 + col] = f2bf(oo);
            }
    }
}

// ---------------------------------------------------------------------------
// Attention phase 2: merge <=8 chunk-partials per q-tile. Grid 512 (batch,qt),
// thread t -> (row = t>>3, 8 cols at (t&7)*8).
__global__ __launch_bounds__(256)
void attn_merge(const float* __restrict__ mp, const float* __restrict__ lp,
                const ushort_t* __restrict__ op, float* __restrict__ out)
{
    const int bq    = blockIdx.x;
    const int batch = bq >> 6;
    const int qt    = bq & 63;
    const int g8    = qt >> 3;
    const int nch   = g8 + 1;
    const int base  = batch * SPB + (g8 + 1) * (qt - 4 * g8);

    const int t   = threadIdx.x;
    const int row = t >> 3;
    const int c8  = (t & 7) * 8;

    float mv[8];
    float M = -INFINITY;
    for (int c = 0; c < nch; ++c) {
        mv[c] = mp[(base + c) * 32 + row];
        M = fmaxf(M, mv[c]);
    }
    float l = 0.f;
    float acc[8] = {0.f, 0.f, 0.f, 0.f, 0.f, 0.f, 0.f, 0.f};
    for (int c = 0; c < nch; ++c) {
        float wgt = __expf(mv[c] - M);
        l += wgt * lp[(base + c) * 32 + row];
        short8 ov = *(const short8*)(op + (size_t)(base + c) * 2048 + row * 64 + c8);
        #pragma unroll
        for (int j = 0; j < 8; ++j) acc[j] += wgt * bf2f((ushort_t)ov[j]);
    }
    const float inv = 1.f / l;
    const size_t grow = (size_t)batch * S + qt * 32 + row;
    float4 o0 = {acc[0]*inv, acc[1]*inv, acc[2]*inv, acc[3]*inv};
    float4 o1 = {acc[4]*inv, acc[5]*inv, acc[6]*inv, acc[7]*inv};
    *(float4*)(out + grow * 64 + c8)     = o0;
    *(float4*)(out + grow * 64 + c8 + 4) = o1;
}

// ---------------------------------------------------------------------------
extern "C" void kernel_launch(void* const* d_in, const int* in_sizes, int n_in,
                              void* d_out, int out_size, void* d_ws, size_t ws_size,
                              hipStream_t stream) {
    const float* x  = (const float*)d_in[0];
    const float* Wk = (const float*)d_in[1];
    const float* Wq = (const float*)d_in[2];
    const float* Wv = (const float*)d_in[3];
    float* out = (float*)d_out;

    ushort_t* qws = (ushort_t*)d_ws;                       // 16384*64 bf16
    ushort_t* kws = qws + (size_t)ROWS * Hd;
    ushort_t* vws = kws + (size_t)ROWS * Hd;
    ushort_t* WT  = vws + (size_t)ROWS * Hd;               // 192*1024 bf16
    float*    mpp = (float*)(WT + (size_t)NTOT * E);       // 2304*32 f32
    float*    lpp = mpp + 8 * SPB * 32;
    ushort_t* opp = (ushort_t*)(lpp + 8 * SPB * 32);       // 2304*2048 bf16

    prep_wt<<<(NTOT * E) / 256, 256, 0, stream>>>(Wk, Wq, Wv, WT);
    proj_mfma<<<ROWS / 16, 256, 0, stream>>>(x, WT, qws, kws, vws);
    attn_part<<<4096, 256, 0, stream>>>(qws, kws, vws, mpp, lpp, opp);
    attn_merge<<<512, 256, 0, stream>>>(mpp, lpp, opp, out);
}